// Round 1
// baseline (927.309 us; speedup 1.0000x reference)
//
#include <hip/hip_runtime.h>

#define NN 50000
#define DD 64
#define EE 800000
#define BB 50
#define NMAXX 1000
#define CC 100

__device__ __forceinline__ float rl(float v, int l) {
  return __int_as_float(__builtin_amdgcn_readlane(__float_as_int(v), l));
}

// K1: msg_up = relu(attr1 @ W_mu + b_mu)   rows = B*C = 5000, each [64]
__global__ __launch_bounds__(256) void k_msgup(
    const float* __restrict__ attr1, const float* __restrict__ Wmu,
    const float* __restrict__ bmu, float* __restrict__ msgup) {
  __shared__ float Wl[64 * 64];
  const int tid = threadIdx.x;
  for (int i = tid; i < 64 * 64; i += 256) Wl[i] = Wmu[i];
  __syncthreads();
  const int lane = tid & 63;
  const int row = blockIdx.x * 4 + (tid >> 6);   // grid 1250 -> rows 0..4999
  float a = attr1[(size_t)row * 64 + lane];
  float acc = bmu[lane];
#pragma unroll 8
  for (int k = 0; k < 64; ++k)
    acc = fmaf(rl(a, k), Wl[k * 64 + lane], acc);
  msgup[(size_t)row * 64 + lane] = fmaxf(acc, 0.f);
}

// K2: agg_up[b,i,:] = sum_c nc1[b,i,c] * msg_up[b,c,:]
// grid = B*16 blocks; block stages msg_up[b] (100x64) in LDS; each wave 16 rows
__global__ __launch_bounds__(256) void k_aggup(
    const float* __restrict__ nc1, const float* __restrict__ msgup,
    float* __restrict__ aggup) {
  __shared__ float Ml[CC * 64];
  const int b = blockIdx.x >> 4;
  const int tile = blockIdx.x & 15;
  const int tid = threadIdx.x;
  for (int i = tid; i < CC * 64; i += 256) Ml[i] = msgup[(size_t)b * CC * 64 + i];
  __syncthreads();
  const int lane = tid & 63;
  const int i0 = tile * 64 + (tid >> 6) * 16;
  size_t roff[16];
#pragma unroll
  for (int t = 0; t < 16; ++t) {
    int i = i0 + t; if (i >= NMAXX) i = NMAXX - 1;   // clamp loads, guard stores
    roff[t] = ((size_t)b * NMAXX + i) * CC;
  }
  float acc[16];
#pragma unroll
  for (int t = 0; t < 16; ++t) acc[t] = 0.f;
  for (int c = 0; c < CC; ++c) {
    float w = Ml[c * 64 + lane];
#pragma unroll
    for (int t = 0; t < 16; ++t)
      acc[t] = fmaf(nc1[roff[t] + c], w, acc[t]);
  }
#pragma unroll
  for (int t = 0; t < 16; ++t) {
    int i = i0 + t;
    if (i < NMAXX) aggup[((size_t)b * NMAXX + i) * 64 + lane] = acc[t];
  }
}

// K3: per edge: msg = relu([x[src], e] @ W_ma + b_ma); atomicAdd into agg[dst]
// grid 12500 x 256; each wave handles 16 edges; W_ma (128x64) in LDS
__global__ __launch_bounds__(256) void k_edge(
    const float* __restrict__ x, const float* __restrict__ e,
    const int* __restrict__ ei, const float* __restrict__ Wma,
    const float* __restrict__ bma, float* __restrict__ agg) {
  __shared__ float Wl[128 * 64];
  const int tid = threadIdx.x;
  for (int i = tid; i < 128 * 64; i += 256) Wl[i] = Wma[i];
  __syncthreads();
  const int lane = tid & 63;
  const int e0 = blockIdx.x * 64 + (tid >> 6) * 16;
  float xv[16], ev[16];
  int dst[16];
#pragma unroll
  for (int t = 0; t < 16; ++t) {
    int eg = e0 + t;
    int src = ei[eg];
    dst[t] = ei[EE + eg];
    xv[t] = x[(size_t)src * 64 + lane];
    ev[t] = e[(size_t)eg * 64 + lane];
  }
  float bn = bma[lane];
  float acc[16];
#pragma unroll
  for (int t = 0; t < 16; ++t) acc[t] = bn;
#pragma unroll 2
  for (int k = 0; k < 64; ++k) {
    float w = Wl[k * 64 + lane];
#pragma unroll
    for (int t = 0; t < 16; ++t)
      acc[t] = fmaf(rl(xv[t], k), w, acc[t]);
  }
#pragma unroll 2
  for (int k = 0; k < 64; ++k) {
    float w = Wl[(64 + k) * 64 + lane];
#pragma unroll
    for (int t = 0; t < 16; ++t)
      acc[t] = fmaf(rl(ev[t], k), w, acc[t]);
  }
#pragma unroll
  for (int t = 0; t < 16; ++t) {
    float m = fmaxf(acc[t], 0.f);
    atomicAdd(&agg[(size_t)dst[t] * 64 + lane], m);
  }
}

// K4: out = concat(relu((agg+ (1+eps1)x)@Wua + bua),
//                  relu((aggup[xidx] + (1+eps2)x)@Wuu + buu)) @ Wc + bc
// grid 3125 x 256; each wave handles 4 rows; Wua,Wuu,Wc in LDS (64 KiB)
__global__ __launch_bounds__(256) void k_final(
    const float* __restrict__ x, const float* __restrict__ agg,
    const float* __restrict__ aggup, const int* __restrict__ xidx,
    const float* __restrict__ eps1, const float* __restrict__ eps2,
    const float* __restrict__ Wua, const float* __restrict__ bua,
    const float* __restrict__ Wuu, const float* __restrict__ buu,
    const float* __restrict__ Wc, const float* __restrict__ bc,
    float* __restrict__ out) {
  __shared__ float W1[64 * 64];
  __shared__ float W2[64 * 64];
  __shared__ float W3[128 * 64];
  const int tid = threadIdx.x;
  for (int i = tid; i < 64 * 64; i += 256) { W1[i] = Wua[i]; W2[i] = Wuu[i]; }
  for (int i = tid; i < 128 * 64; i += 256) W3[i] = Wc[i];
  __syncthreads();
  const int lane = tid & 63;
  const int r0 = blockIdx.x * 16 + (tid >> 6) * 4;
  const float s1 = 1.f + eps1[0], s2 = 1.f + eps2[0];
  float h1[4], h2[4];
#pragma unroll
  for (int t = 0; t < 4; ++t) {
    int r = r0 + t;
    float xv = x[(size_t)r * 64 + lane];
    h1[t] = agg[(size_t)r * 64 + lane] + s1 * xv;
    h2[t] = aggup[(size_t)xidx[r] * 64 + lane] + s2 * xv;
  }
  float a1[4], a2[4];
  float b1 = bua[lane], b2 = buu[lane];
#pragma unroll
  for (int t = 0; t < 4; ++t) { a1[t] = b1; a2[t] = b2; }
#pragma unroll 4
  for (int k = 0; k < 64; ++k) {
    float w1 = W1[k * 64 + lane];
    float w2 = W2[k * 64 + lane];
#pragma unroll
    for (int t = 0; t < 4; ++t) {
      a1[t] = fmaf(rl(h1[t], k), w1, a1[t]);
      a2[t] = fmaf(rl(h2[t], k), w2, a2[t]);
    }
  }
  float o1[4], o2[4];
#pragma unroll
  for (int t = 0; t < 4; ++t) {
    o1[t] = fmaxf(a1[t], 0.f);
    o2[t] = fmaxf(a2[t], 0.f);
  }
  float acc[4];
  float b3 = bc[lane];
#pragma unroll
  for (int t = 0; t < 4; ++t) acc[t] = b3;
#pragma unroll 4
  for (int k = 0; k < 64; ++k) {
    float wc1 = W3[k * 64 + lane];
    float wc2 = W3[(64 + k) * 64 + lane];
#pragma unroll
    for (int t = 0; t < 4; ++t) {
      acc[t] = fmaf(rl(o1[t], k), wc1, acc[t]);
      acc[t] = fmaf(rl(o2[t], k), wc2, acc[t]);
    }
  }
#pragma unroll
  for (int t = 0; t < 4; ++t)
    out[(size_t)(r0 + t) * 64 + lane] = acc[t];
}

extern "C" void kernel_launch(void* const* d_in, const int* in_sizes, int n_in,
                              void* d_out, int out_size, void* d_ws, size_t ws_size,
                              hipStream_t stream) {
  const float* x     = (const float*)d_in[0];
  const float* e     = (const float*)d_in[1];
  const int*   ei    = (const int*)d_in[2];
  const float* attr1 = (const float*)d_in[3];
  const float* nc1   = (const float*)d_in[4];
  const int*   xidx  = (const int*)d_in[5];
  const float* eps1  = (const float*)d_in[6];
  const float* eps2  = (const float*)d_in[7];
  const float* Wma   = (const float*)d_in[8];
  const float* bma   = (const float*)d_in[9];
  const float* Wmu   = (const float*)d_in[10];
  const float* bmu   = (const float*)d_in[11];
  const float* Wua   = (const float*)d_in[12];
  const float* bua   = (const float*)d_in[13];
  const float* Wuu   = (const float*)d_in[14];
  const float* buu   = (const float*)d_in[15];
  const float* Wc    = (const float*)d_in[16];
  const float* bc    = (const float*)d_in[17];
  float* out = (float*)d_out;

  float* agg   = (float*)d_ws;                 // [N,64] adjacency aggregate
  float* aggup = agg + (size_t)NN * 64;        // [N,64] pooled aggregate
  float* msgup = aggup + (size_t)NN * 64;      // [5000,64] cluster messages

  hipMemsetAsync(agg, 0, (size_t)NN * 64 * sizeof(float), stream);
  k_msgup<<<dim3(1250), dim3(256), 0, stream>>>(attr1, Wmu, bmu, msgup);
  k_aggup<<<dim3(BB * 16), dim3(256), 0, stream>>>(nc1, msgup, aggup);
  k_edge<<<dim3(12500), dim3(256), 0, stream>>>(x, e, ei, Wma, bma, agg);
  k_final<<<dim3(3125), dim3(256), 0, stream>>>(x, agg, aggup, xidx, eps1, eps2,
                                                Wua, bua, Wuu, buu, Wc, bc, out);
}

// Round 2
// 594.704 us; speedup vs baseline: 1.5593x; 1.5593x over previous
//
#include <hip/hip_runtime.h>

#define NN 50000
#define DD 64
#define EE 800000
#define BB 50
#define NMAXX 1000
#define CC 100

typedef short short8 __attribute__((ext_vector_type(8)));
typedef float float4v __attribute__((ext_vector_type(4)));

__device__ __forceinline__ float rl(float v, int l) {
  return __int_as_float(__builtin_amdgcn_readlane(__float_as_int(v), l));
}

// f32 -> bf16 round-to-nearest-even (bit trick, finite inputs)
__device__ __forceinline__ short f2bf(float f) {
  unsigned u = __float_as_uint(f);
  unsigned r = (u + 0x7fffu + ((u >> 16) & 1u)) >> 16;
  return (short)r;
}
__device__ __forceinline__ unsigned pack2(float a, float b) {
  return (unsigned)(unsigned short)f2bf(a) |
         ((unsigned)(unsigned short)f2bf(b) << 16);
}

// K1: msg_up = relu(attr1 @ W_mu + b_mu)   rows = B*C = 5000, each [64]
__global__ __launch_bounds__(256) void k_msgup(
    const float* __restrict__ attr1, const float* __restrict__ Wmu,
    const float* __restrict__ bmu, float* __restrict__ msgup) {
  __shared__ float Wl[64 * 64];
  const int tid = threadIdx.x;
  for (int i = tid; i < 64 * 64; i += 256) Wl[i] = Wmu[i];
  __syncthreads();
  const int lane = tid & 63;
  const int row = blockIdx.x * 4 + (tid >> 6);   // grid 1250 -> rows 0..4999
  float a = attr1[(size_t)row * 64 + lane];
  float acc = bmu[lane];
#pragma unroll 8
  for (int k = 0; k < 64; ++k)
    acc = fmaf(rl(a, k), Wl[k * 64 + lane], acc);
  msgup[(size_t)row * 64 + lane] = fmaxf(acc, 0.f);
}

// K2: agg_up[b,i,:] = sum_c nc1[b,i,c] * msg_up[b,c,:]
// grid = B*16; block stages msg_up[b] (100x64) AND nc1 tile (64x100) in LDS
__global__ __launch_bounds__(256) void k_aggup(
    const float* __restrict__ nc1, const float* __restrict__ msgup,
    float* __restrict__ aggup) {
  __shared__ float Ml[CC * 64];   // 25.6 KB
  __shared__ float Nc[64 * CC];   // 25.6 KB
  const int b = blockIdx.x >> 4;
  const int tile = blockIdx.x & 15;
  const int tid = threadIdx.x;
  const int i0 = tile * 64;
  for (int i = tid; i < CC * 64; i += 256) Ml[i] = msgup[(size_t)b * CC * 64 + i];
  const float* ncb = nc1 + ((size_t)b * NMAXX + i0) * CC;
  for (int idx = tid; idx < 64 * CC; idx += 256) {
    int r = idx / CC;
    Nc[idx] = (i0 + r < NMAXX) ? ncb[idx] : 0.f;
  }
  __syncthreads();
  const int lane = tid & 63;
  const int t0 = (tid >> 6) * 16;      // wave handles rows t0..t0+15
  float acc[16];
#pragma unroll
  for (int t = 0; t < 16; ++t) acc[t] = 0.f;
  for (int c = 0; c < CC; ++c) {
    float w = Ml[c * 64 + lane];
#pragma unroll
    for (int t = 0; t < 16; ++t)
      acc[t] = fmaf(Nc[(t0 + t) * CC + c], w, acc[t]);
  }
#pragma unroll
  for (int t = 0; t < 16; ++t) {
    int i = i0 + t0 + t;
    if (i < NMAXX) aggup[((size_t)b * NMAXX + i) * 64 + lane] = acc[t];
  }
}

// K3 (MFMA): per 64-edge tile: A = bf16([x[src] | e]) [64x128],
// B = bf16(W_ma^T) [64 cols x 128 k]; C[64x64] = relu(A@W + b); atomic scatter.
__global__ __launch_bounds__(256) void k_edge_mfma(
    const float* __restrict__ x, const float* __restrict__ e,
    const int* __restrict__ ei, const float* __restrict__ Wma,
    const float* __restrict__ bma, float* __restrict__ agg) {
  constexpr int LDA = 136;           // 128 + 8 bf16 pad (4-bank shift)
  __shared__ short A[64 * LDA];      // 17.4 KB
  __shared__ short Wt[64 * LDA];     // 17.4 KB  (Wt[n][k] = W_ma[k][n])
  __shared__ int dstS[64];
  const int tid = threadIdx.x;
  // stage W transposed as bf16 (once per block, L2-hit)
  for (int idx = tid; idx < 128 * 64; idx += 256) {
    int k = idx >> 6, n = idx & 63;
    Wt[n * LDA + k] = f2bf(Wma[idx]);
  }
  // stage A: thread t -> edge t>>2, 32-float part t&3 (x lo/hi, e lo/hi)
  const int e0 = blockIdx.x * 64;
  {
    const int edge = tid >> 2;
    const int part = tid & 3;
    const int eg = e0 + edge;
    if (part == 0) dstS[edge] = ei[EE + eg];
    const float* srcp;
    if (part < 2) {
      int src = ei[eg];
      srcp = x + (size_t)src * 64 + part * 32;
    } else {
      srcp = e + (size_t)eg * 64 + (part - 2) * 32;
    }
    unsigned* dstA = (unsigned*)(A + edge * LDA + part * 32);
#pragma unroll
    for (int j = 0; j < 8; ++j) {
      float4 v = ((const float4*)srcp)[j];
      unsigned lo = pack2(v.x, v.y);
      unsigned hi = pack2(v.z, v.w);
      ((uint2*)dstA)[j] = make_uint2(lo, hi);
    }
  }
  __syncthreads();
  const int lane = tid & 63;
  const int w = tid >> 6;            // wave id: edges w*16 .. w*16+15
  const int m = lane & 15;
  const int koff = (lane >> 4) * 8;
  float4v acc[4];
#pragma unroll
  for (int cb = 0; cb < 4; ++cb) acc[cb] = (float4v)0.f;
#pragma unroll
  for (int ks = 0; ks < 4; ++ks) {
    short8 af = *(const short8*)&A[(w * 16 + m) * LDA + ks * 32 + koff];
#pragma unroll
    for (int cb = 0; cb < 4; ++cb) {
      short8 bf = *(const short8*)&Wt[(cb * 16 + m) * LDA + ks * 32 + koff];
      acc[cb] = __builtin_amdgcn_mfma_f32_16x16x32_bf16(af, bf, acc[cb], 0, 0, 0);
    }
  }
  // C layout: col = cb*16 + (lane&15), row(edge_local) = (lane>>4)*4 + r
  const int rbase = (lane >> 4) * 4;
#pragma unroll
  for (int cb = 0; cb < 4; ++cb) {
    float bias = bma[cb * 16 + m];
#pragma unroll
    for (int r = 0; r < 4; ++r) {
      int dst = dstS[w * 16 + rbase + r];
      float v = fmaxf(acc[cb][r] + bias, 0.f);
      if (v > 0.f)   // relu zeros ~50% -> masked-lane atomics halve traffic
        atomicAdd(&agg[(size_t)dst * 64 + cb * 16 + m], v);
    }
  }
}

// K4: out = concat(relu((agg+(1+eps1)x)@Wua+bua),
//                  relu((aggup[xidx]+(1+eps2)x)@Wuu+buu)) @ Wc + bc
__global__ __launch_bounds__(256) void k_final(
    const float* __restrict__ x, const float* __restrict__ agg,
    const float* __restrict__ aggup, const int* __restrict__ xidx,
    const float* __restrict__ eps1, const float* __restrict__ eps2,
    const float* __restrict__ Wua, const float* __restrict__ bua,
    const float* __restrict__ Wuu, const float* __restrict__ buu,
    const float* __restrict__ Wc, const float* __restrict__ bc,
    float* __restrict__ out) {
  __shared__ float W1[64 * 64];
  __shared__ float W2[64 * 64];
  __shared__ float W3[128 * 64];
  const int tid = threadIdx.x;
  for (int i = tid; i < 64 * 64; i += 256) { W1[i] = Wua[i]; W2[i] = Wuu[i]; }
  for (int i = tid; i < 128 * 64; i += 256) W3[i] = Wc[i];
  __syncthreads();
  const int lane = tid & 63;
  const int r0 = blockIdx.x * 16 + (tid >> 6) * 4;
  const float s1 = 1.f + eps1[0], s2 = 1.f + eps2[0];
  float h1[4], h2[4];
#pragma unroll
  for (int t = 0; t < 4; ++t) {
    int r = r0 + t;
    float xv = x[(size_t)r * 64 + lane];
    h1[t] = agg[(size_t)r * 64 + lane] + s1 * xv;
    h2[t] = aggup[(size_t)xidx[r] * 64 + lane] + s2 * xv;
  }
  float a1[4], a2[4];
  float b1 = bua[lane], b2 = buu[lane];
#pragma unroll
  for (int t = 0; t < 4; ++t) { a1[t] = b1; a2[t] = b2; }
#pragma unroll 4
  for (int k = 0; k < 64; ++k) {
    float w1 = W1[k * 64 + lane];
    float w2 = W2[k * 64 + lane];
#pragma unroll
    for (int t = 0; t < 4; ++t) {
      a1[t] = fmaf(rl(h1[t], k), w1, a1[t]);
      a2[t] = fmaf(rl(h2[t], k), w2, a2[t]);
    }
  }
  float o1[4], o2[4];
#pragma unroll
  for (int t = 0; t < 4; ++t) {
    o1[t] = fmaxf(a1[t], 0.f);
    o2[t] = fmaxf(a2[t], 0.f);
  }
  float acc[4];
  float b3 = bc[lane];
#pragma unroll
  for (int t = 0; t < 4; ++t) acc[t] = b3;
#pragma unroll 4
  for (int k = 0; k < 64; ++k) {
    float wc1 = W3[k * 64 + lane];
    float wc2 = W3[(64 + k) * 64 + lane];
#pragma unroll
    for (int t = 0; t < 4; ++t) {
      acc[t] = fmaf(rl(o1[t], k), wc1, acc[t]);
      acc[t] = fmaf(rl(o2[t], k), wc2, acc[t]);
    }
  }
#pragma unroll
  for (int t = 0; t < 4; ++t)
    out[(size_t)(r0 + t) * 64 + lane] = acc[t];
}

extern "C" void kernel_launch(void* const* d_in, const int* in_sizes, int n_in,
                              void* d_out, int out_size, void* d_ws, size_t ws_size,
                              hipStream_t stream) {
  const float* x     = (const float*)d_in[0];
  const float* e     = (const float*)d_in[1];
  const int*   ei    = (const int*)d_in[2];
  const float* attr1 = (const float*)d_in[3];
  const float* nc1   = (const float*)d_in[4];
  const int*   xidx  = (const int*)d_in[5];
  const float* eps1  = (const float*)d_in[6];
  const float* eps2  = (const float*)d_in[7];
  const float* Wma   = (const float*)d_in[8];
  const float* bma   = (const float*)d_in[9];
  const float* Wmu   = (const float*)d_in[10];
  const float* bmu   = (const float*)d_in[11];
  const float* Wua   = (const float*)d_in[12];
  const float* bua   = (const float*)d_in[13];
  const float* Wuu   = (const float*)d_in[14];
  const float* buu   = (const float*)d_in[15];
  const float* Wc    = (const float*)d_in[16];
  const float* bc    = (const float*)d_in[17];
  float* out = (float*)d_out;

  float* agg   = (float*)d_ws;                 // [N,64] adjacency aggregate
  float* aggup = agg + (size_t)NN * 64;        // [N,64] pooled aggregate
  float* msgup = aggup + (size_t)NN * 64;      // [5000,64] cluster messages

  hipMemsetAsync(agg, 0, (size_t)NN * 64 * sizeof(float), stream);
  k_msgup<<<dim3(1250), dim3(256), 0, stream>>>(attr1, Wmu, bmu, msgup);
  k_aggup<<<dim3(BB * 16), dim3(256), 0, stream>>>(nc1, msgup, aggup);
  k_edge_mfma<<<dim3(EE / 64), dim3(256), 0, stream>>>(x, e, ei, Wma, bma, agg);
  k_final<<<dim3(3125), dim3(256), 0, stream>>>(x, agg, aggup, xidx, eps1, eps2,
                                                Wua, bua, Wuu, buu, Wc, bc, out);
}